// Round 4
// baseline (35.147 us; speedup 1.0000x reference)
//
#include <hip/hip_runtime.h>

#define NPTS 4096
#define BATCH 8
#define YC 256          // Y points staged in LDS per block
#define YP (YC/2)       // 128 Y pairs
#define QPB 2048        // queries per block
#define QPT 8           // queries per thread
#define YCH 16          // NPTS / YC
#define QCH 2           // NPTS / QPB
#define BIGF 1e10f

typedef float f2 __attribute__((ext_vector_type(2)));

// Kernel A: for each (dir, b, qc, yc) block, partial min over its Y-chunk of
//   d = x2 + y2 + penalty - 2 x.y  ->  pmin[((dir*8+b)*16+yc)*NPTS + n].
// dir 0: X = clean = points+target, Y = predp = points+pred   (-> min_x)
// dir 1: X = predp = points+pred,  Y = clean = points+target  (-> min_y)
// Inner loop: f2 lanes hold a PAIR of Y points; query coeffs splat outside the
// loop -> 3 v_pk_fma_f32 + 1 v_min3_f32 per (2 Y x 1 query). QPT=8 amortizes
// each LDS broadcast read over 8 queries (LDS return bytes/pair = 2 B).
__global__ __launch_bounds__(256) void chamfer_partial_kernel(
    const float* __restrict__ pred, const float* __restrict__ target,
    const int* __restrict__ mask, const float* __restrict__ points,
    float* __restrict__ pmin, float* __restrict__ out)
{
    __shared__ float4 tA[YP];   // (x0, x1, y0, y1)
    __shared__ float4 tB[YP];   // (z0, z1, w0, w1)

    if (blockIdx.x == 0 && threadIdx.x == 0) out[0] = 0.0f;  // re-zeroed every replay

    int bid = blockIdx.x;
    int yc  = bid & 15; bid >>= 4;
    int qc  = bid & 1;  bid >>= 1;
    int b   = bid & 7;  bid >>= 3;
    int dir = bid;

    const float* __restrict__ yres = dir ? target : pred;
    const float* __restrict__ xres = dir ? pred : target;

    int t = threadIdx.x;

    // stage Y pairs: threads 0..127 each stage one pair (2 points)
    if (t < YP) {
        int g0 = b * NPTS + yc * YC + 2 * t;
        float x0 = points[g0 * 3 + 0] + yres[g0 * 3 + 0];
        float y0 = points[g0 * 3 + 1] + yres[g0 * 3 + 1];
        float z0 = points[g0 * 3 + 2] + yres[g0 * 3 + 2];
        float x1 = points[g0 * 3 + 3] + yres[g0 * 3 + 3];
        float y1 = points[g0 * 3 + 4] + yres[g0 * 3 + 4];
        float z1 = points[g0 * 3 + 5] + yres[g0 * 3 + 5];
        float w0 = x0 * x0 + y0 * y0 + z0 * z0;
        float w1 = x1 * x1 + y1 * y1 + z1 * z1;
        if (!mask[g0])     w0 += BIGF;
        if (!mask[g0 + 1]) w1 += BIGF;
        tA[t] = make_float4(x0, x1, y0, y1);
        tB[t] = make_float4(z0, z1, w0, w1);
    }
    __syncthreads();

    // queries: -2*x components splat to both f2 lanes; x2 scalar
    f2 q2x[QPT], q2y[QPT], q2z[QPT];
    float x2[QPT], mn[QPT];
#pragma unroll
    for (int k = 0; k < QPT; k++) {
        int g = b * NPTS + qc * QPB + k * 256 + t;
        float qx = points[g * 3 + 0] + xres[g * 3 + 0];
        float qy = points[g * 3 + 1] + xres[g * 3 + 1];
        float qz = points[g * 3 + 2] + xres[g * 3 + 2];
        x2[k] = qx * qx + qy * qy + qz * qz;
        float ax = -2.0f * qx, ay = -2.0f * qy, az = -2.0f * qz;
        q2x[k] = (f2){ax, ax};
        q2y[k] = (f2){ay, ay};
        q2z[k] = (f2){az, az};
        mn[k]  = 3.0e38f;
    }

#pragma unroll 2
    for (int j = 0; j < YP; j++) {
        float4 A = tA[j];   // uniform address -> LDS broadcast
        float4 B = tB[j];
        f2 yx = (f2){A.x, A.y};
        f2 yy = (f2){A.z, A.w};
        f2 yz = (f2){B.x, B.y};
        f2 yw = (f2){B.z, B.w};
#pragma unroll
        for (int k = 0; k < QPT; k++) {
            f2 e = __builtin_elementwise_fma(q2z[k], yz,
                   __builtin_elementwise_fma(q2y[k], yy,
                   __builtin_elementwise_fma(q2x[k], yx, yw)));
            mn[k] = fminf(fminf(mn[k], e.x), e.y);   // -> v_min3_f32
        }
    }

    float* base = pmin + ((dir * 8 + b) * 16 + yc) * NPTS + qc * QPB;
#pragma unroll
    for (int k = 0; k < QPT; k++) {
        base[k * 256 + t] = x2[k] + mn[k];  // clamped >= 0 in reduce
    }
}

// Kernel B: one block per batch. Min the 16 yc-partials per dir, clamp,
// row-mask, sum & count, then one atomicAdd of (S/C)/BATCH into out.
__global__ __launch_bounds__(1024) void reduce_kernel(
    const int* __restrict__ mask, const float* __restrict__ pmin,
    float* __restrict__ out)
{
    __shared__ float s_sum[16], s_cnt[16];
    int b = blockIdx.x;
    int t = threadIdx.x;

    float sum = 0.0f, cnt = 0.0f;
#pragma unroll
    for (int s = 0; s < 4; s++) {
        int n = s * 1024 + t;
        if (mask[b * NPTS + n]) {
            const float* p0 = pmin + ((0 * 8 + b) * 16) * NPTS + n;
            const float* p1 = pmin + ((1 * 8 + b) * 16) * NPTS + n;
            float m0 = p0[0], m1 = p1[0];
#pragma unroll
            for (int yc = 1; yc < 16; yc++) {
                m0 = fminf(m0, p0[yc * NPTS]);
                m1 = fminf(m1, p1[yc * NPTS]);
            }
            sum += fmaxf(m0, 0.0f) + fmaxf(m1, 0.0f);
            cnt += 1.0f;
        }
    }
    for (int off = 32; off; off >>= 1) {
        sum += __shfl_down(sum, off, 64);
        cnt += __shfl_down(cnt, off, 64);
    }
    if ((t & 63) == 0) { s_sum[t >> 6] = sum; s_cnt[t >> 6] = cnt; }
    __syncthreads();
    if (t == 0) {
        float S = 0.0f, C = 0.0f;
#pragma unroll
        for (int w = 0; w < 16; w++) { S += s_sum[w]; C += s_cnt[w]; }
        atomicAdd(out, (S / C) * (1.0f / (float)BATCH));
    }
}

extern "C" void kernel_launch(void* const* d_in, const int* in_sizes, int n_in,
                              void* d_out, int out_size, void* d_ws, size_t ws_size,
                              hipStream_t stream) {
    const float* pred   = (const float*)d_in[0];
    const float* target = (const float*)d_in[1];
    const int*   mask   = (const int*)d_in[2];
    const float* points = (const float*)d_in[3];
    float* out = (float*)d_out;

    float* pmin = (float*)d_ws;   // 2*8*16*4096 floats = 4 MB

    chamfer_partial_kernel<<<2 * BATCH * QCH * YCH, 256, 0, stream>>>(pred, target, mask, points, pmin, out);
    reduce_kernel<<<BATCH, 1024, 0, stream>>>(mask, pmin, out);
}